// Round 5
// baseline (196.510 us; speedup 1.0000x reference)
//
#include <hip/hip_runtime.h>

#define NPTS 1024
#define BATCH 8
#define BPB 32                 // blocks per batch
#define NBLOCKS (BATCH * BPB)  // 256 blocks = 1/CU, all co-resident
#define NTHREADS 512           // 8 waves
#define WPB 8
#define RPW 4                  // rows per wave: 32*8*4 = 1024
#define KCH 16                 // 1024/64 chunks per lane

#define SCOPE_AGENT __HIP_MEMORY_SCOPE_AGENT
#define SCOPE_WG    __HIP_MEMORY_SCOPE_WORKGROUP

typedef unsigned long long ull;

constexpr float REG_ = 0.1f;
constexpr float LOG2E = 1.4426950408889634f;

__device__ __forceinline__ float wave_sum(float x) {
    #pragma unroll
    for (int off = 32; off; off >>= 1) x += __shfl_xor(x, off);
    return x;
}
__device__ __forceinline__ float wave_max(float x) {
    #pragma unroll
    for (int off = 32; off; off >>= 1) x = fmaxf(x, __shfl_xor(x, off));
    return x;
}

// Fetch this wave's 2 assigned 64-element chunks of {value,epoch} atoms from
// global, spin until epoch >= ep (dataflow sync -- exact match guaranteed by
// the Sinkhorn dependency chain), deposit values in LDS, publish chunk flags.
__device__ __forceinline__ void fetch2(const ull* __restrict__ gsrc,
                                       float* __restrict__ lds,
                                       int* __restrict__ lflag,
                                       int w, int lane, unsigned ep) {
    int t0 = (w * 2) * 64 + lane;
    int t1 = t0 + 64;
    ull r0 = 0, r1 = 0;
    bool d0 = false, d1 = false;
    for (;;) {
        if (!d0) { r0 = __hip_atomic_load(&gsrc[t0], __ATOMIC_RELAXED, SCOPE_AGENT);
                   d0 = (int)((unsigned)(r0 >> 32) - ep) >= 0; }
        if (!d1) { r1 = __hip_atomic_load(&gsrc[t1], __ATOMIC_RELAXED, SCOPE_AGENT);
                   d1 = (int)((unsigned)(r1 >> 32) - ep) >= 0; }
        if (__all(d0 && d1)) break;
        __builtin_amdgcn_s_sleep(1);
    }
    lds[t0] = __uint_as_float((unsigned)r0);
    lds[t1] = __uint_as_float((unsigned)r1);
    __threadfence_block();   // data before flag
    if (lane == 0) {
        __hip_atomic_store(&lflag[w * 2],     (int)ep, __ATOMIC_RELEASE, SCOPE_WG);
        __hip_atomic_store(&lflag[w * 2 + 1], (int)ep, __ATOMIC_RELEASE, SCOPE_WG);
    }
}

__device__ __forceinline__ void wait_flags(const int* __restrict__ lflag,
                                           int lane, unsigned ep) {
    if (lane < KCH)
        while ((int)(__hip_atomic_load(&lflag[lane], __ATOMIC_ACQUIRE, SCOPE_WG)
                     - (int)ep) < 0) {}
}

__global__ __launch_bounds__(NTHREADS, 2) void sinkhorn_fused(
    const float2* __restrict__ c1g, const float* __restrict__ p1g,
    const float2* __restrict__ c2g, const float* __restrict__ p2g,
    float* __restrict__ out, unsigned* __restrict__ pmax_all,
    ull* __restrict__ upk_all, ull* __restrict__ vpk_all)
{
    const int tid  = threadIdx.x;
    const int lane = tid & 63;
    const int w    = tid >> 6;
    const int bid  = blockIdx.x & (BATCH - 1);  // XCD-local batches
    const int sub  = blockIdx.x >> 3;
    const int gb   = bid << 10;
    const int r0   = sub * 32 + w * RPW;

    unsigned* pmax = pmax_all + bid * BPB;
    ull* upk = upk_all + gb;
    ull* vpk = vpk_all + gb;

    __shared__ float xeu[NPTS];
    __shared__ float xev[NPTS];
    __shared__ int   flu[KCH];
    __shared__ int   flv[KCH];
    __shared__ float red[WPB];

    if (tid < KCH) { flu[tid] = 0; flv[tid] = 0; }

    // ---- prob sums: every wave covers all 1024 ----
    float s1 = 0.f, s2 = 0.f;
    #pragma unroll
    for (int k = 0; k < KCH; ++k) {
        int t = lane + 64 * k;
        s1 += p1g[gb + t] + 1e-8f;
        s2 += p2g[gb + t] + 1e-8f;
    }
    s1 = wave_sum(s1);
    s2 = wave_sum(s2);

    // ---- per-row data (wave-uniform loads) ----
    float rc1x[RPW], rc1y[RPW], rc2x[RPW], rc2y[RPW], pa[RPW], pb[RPW];
    #pragma unroll
    for (int i = 0; i < RPW; ++i) {
        float2 c1 = c1g[gb + r0 + i];
        float2 c2 = c2g[gb + r0 + i];
        rc1x[i] = c1.x; rc1y[i] = c1.y;
        rc2x[i] = c2.x; rc2y[i] = c2.y;
        pa[i] = (p1g[gb + r0 + i] + 1e-8f) / s1;
        pb[i] = (p2g[gb + r0 + i] + 1e-8f) / s2;
    }

    // ---- Ku d2 (own c1 rows x all c2) -> also the mmax source ----
    float Ku[RPW][KCH], Kv[RPW][KCH];
    float m = 0.f;
    #pragma unroll
    for (int k = 0; k < KCH; ++k) {
        float2 c2 = c2g[gb + lane + 64 * k];
        #pragma unroll
        for (int i = 0; i < RPW; ++i) {
            float dx = rc1x[i] - c2.x, dy = rc1y[i] - c2.y;
            float d2 = dx * dx + dy * dy;
            Ku[i][k] = d2;
            m = fmaxf(m, d2);
        }
    }
    m = wave_max(m);
    if (lane == 0) red[w] = m;
    __syncthreads();   // also covers flu/flv init
    if (tid == 0) {
        float bm = red[0];
        #pragma unroll
        for (int i = 1; i < WPB; ++i) bm = fmaxf(bm, red[i]);
        __hip_atomic_store(&pmax[sub], __float_as_uint(bm),
                           __ATOMIC_RELEASE, SCOPE_AGENT);
    }

    // ---- Kv d2 (own c2 rows x all c1) while other blocks' maxes arrive ----
    #pragma unroll
    for (int k = 0; k < KCH; ++k) {
        float2 c1 = c1g[gb + lane + 64 * k];
        #pragma unroll
        for (int i = 0; i < RPW; ++i) {
            float dx = rc2x[i] - c1.x, dy = rc2y[i] - c1.y;
            Kv[i][k] = dx * dx + dy * dy;
        }
    }

    // ---- mmax: every wave polls the 32 block-partials (poison is negative) ----
    unsigned pv;
    for (;;) {
        pv = (lane < BPB)
            ? __hip_atomic_load(&pmax[lane], __ATOMIC_RELAXED, SCOPE_AGENT) : 0u;
        if (__all((int)pv >= 0)) break;
        __builtin_amdgcn_s_sleep(1);
    }
    const float mmax = wave_max((lane < BPB) ? __uint_as_float(pv) : 0.f);
    const float nIL2 = -LOG2E / (REG_ * mmax);

    // ---- exponentiate once: K cached in registers for all 20 phases + P ----
    #pragma unroll
    for (int k = 0; k < KCH; ++k) {
        #pragma unroll
        for (int i = 0; i < RPW; ++i) {
            Ku[i][k] = exp2f(nIL2 * Ku[i][k]);
            Kv[i][k] = exp2f(nIL2 * Kv[i][k]);
        }
    }

    // ---- 10 Sinkhorn iterations, barrier-free dataflow sync ----
    float xer[KCH];
    float accu[RPW];
    for (int it = 0; it < 10; ++it) {
        // v-phase: v_j = pb_j / sum_t K_tj * u_t   (consumes u@it)
        if (it == 0) {
            #pragma unroll
            for (int k = 0; k < KCH; ++k) xer[k] = 1.0f / NPTS;
        } else {
            fetch2(upk, xeu, flu, w, lane, (unsigned)it);
            wait_flags(flu, lane, (unsigned)it);
            #pragma unroll
            for (int k = 0; k < KCH; ++k) xer[k] = xeu[lane + 64 * k];
        }
        float acc[RPW] = {0.f, 0.f, 0.f, 0.f};
        #pragma unroll
        for (int k = 0; k < KCH; ++k) {
            #pragma unroll
            for (int i = 0; i < RPW; ++i)
                acc[i] = fmaf(Kv[i][k], xer[k], acc[i]);
        }
        #pragma unroll
        for (int i = 0; i < RPW; ++i) acc[i] = wave_sum(acc[i]);
        if (lane == 0) {
            #pragma unroll
            for (int i = 0; i < RPW; ++i)
                __hip_atomic_store(&vpk[r0 + i],
                    ((ull)(unsigned)(it + 1) << 32) |
                     (ull)__float_as_uint(pb[i] / acc[i]),
                    __ATOMIC_RELAXED, SCOPE_AGENT);
        }

        // u-phase: u_i = pa_i / sum_t K_it * v_t   (consumes v@it+1)
        fetch2(vpk, xev, flv, w, lane, (unsigned)(it + 1));
        wait_flags(flv, lane, (unsigned)(it + 1));
        #pragma unroll
        for (int k = 0; k < KCH; ++k) xer[k] = xev[lane + 64 * k];
        #pragma unroll
        for (int i = 0; i < RPW; ++i) accu[i] = 0.f;
        #pragma unroll
        for (int k = 0; k < KCH; ++k) {
            #pragma unroll
            for (int i = 0; i < RPW; ++i)
                accu[i] = fmaf(Ku[i][k], xer[k], accu[i]);
        }
        #pragma unroll
        for (int i = 0; i < RPW; ++i) accu[i] = wave_sum(accu[i]);
        if (it < 9) {   // final u stays in registers
            if (lane == 0) {
                #pragma unroll
                for (int i = 0; i < RPW; ++i)
                    __hip_atomic_store(&upk[r0 + i],
                        ((ull)(unsigned)(it + 1) << 32) |
                         (ull)__float_as_uint(pa[i] / accu[i]),
                        __ATOMIC_RELAXED, SCOPE_AGENT);
            }
        }
    }

    // ---- P-write: P[r][j] = (pa_r/accu_r) * Ku[r][j] * v_j (xer = v@10) ----
    float rowu[RPW];
    #pragma unroll
    for (int i = 0; i < RPW; ++i) rowu[i] = pa[i] / accu[i];
    const long ob = ((long)bid << 20) + ((long)r0 << 10);
    #pragma unroll
    for (int k = 0; k < KCH; ++k) {
        #pragma unroll
        for (int i = 0; i < RPW; ++i) {
            __builtin_nontemporal_store(rowu[i] * Ku[i][k] * xer[k],
                &out[ob + (i << 10) + lane + 64 * k]);
        }
    }
}

extern "C" void kernel_launch(void* const* d_in, const int* in_sizes, int n_in,
                              void* d_out, int out_size, void* d_ws, size_t ws_size,
                              hipStream_t stream) {
    const float2* c1 = (const float2*)d_in[0];  // coord1 [8,1024,2]
    const float*  p1 = (const float*)d_in[1];   // prob1  [8,1024]
    const float2* c2 = (const float2*)d_in[2];  // coord2 [8,1024,2]
    const float*  p2 = (const float*)d_in[3];   // prob2  [8,1024]
    float* out = (float*)d_out;                 // P [8,1024,1024]

    // ws: [0,1KB)      pmax slots (8 batches x 32 blocks)
    //     [1KB,65KB)   upk {value,epoch} atoms (8 x 1024 x 8B)
    //     [65KB,129KB) vpk atoms
    // No memset: all protocols are 0xAA-poison-safe (epoch/payload words
    // are negative as int until first genuine store).
    unsigned* pmax = (unsigned*)d_ws;
    ull* upk = (ull*)((char*)d_ws + 1024);
    ull* vpk = upk + BATCH * NPTS;

    sinkhorn_fused<<<NBLOCKS, NTHREADS, 0, stream>>>(c1, p1, c2, p2, out,
                                                     pmax, upk, vpk);
}